// Round 2
// baseline (458.411 us; speedup 1.0000x reference)
//
#include <hip/hip_runtime.h>
#include <stdint.h>

typedef unsigned short u16;
typedef __attribute__((ext_vector_type(8))) __bf16 bf16x8;
typedef __attribute__((ext_vector_type(4))) float f32x4;

#define BM 128
#define BN 128
#define BK 64

__device__ __forceinline__ u16 f2bf(float f) {
    uint32_t u = __float_as_uint(f);
    u += 0x7FFF + ((u >> 16) & 1);   // RNE
    return (u16)(u >> 16);
}
__device__ __forceinline__ float bf2f(u16 b) {
    return __uint_as_float(((uint32_t)b) << 16);
}
__device__ __forceinline__ float h2f(u16 h) {
    float r; uint32_t x = h;
    asm volatile("v_cvt_f32_f16_e32 %0, %1" : "=v"(r) : "v"(x));
    return r;
}
__device__ __forceinline__ u16 f2h(float f) {
    uint32_t r;
    asm volatile("v_cvt_f16_f32_e32 %0, %1" : "=v"(r) : "v"(f));
    return (u16)r;
}

// ---------------- dtype detection (deterministic, data-driven) ----------------
// flags[0]: x/bias/out mode: 0=float32, 1=bf16(u16), 2=fp16(u16)
// flags[1]: qweight mode:    0=packed bytes, 1=one byte per int32
__global__ void detect_kernel(const uint32_t* __restrict__ xw,
                              const uint32_t* __restrict__ qw,
                              int* __restrict__ flags) {
    if (blockIdx.x | threadIdx.x) return;
    bool allz = true;
    for (int i = 0; i < 64; ++i) allz = allz && ((xw[i] & 0x1FFFu) == 0u);
    int mode;
    if (allz) mode = 0;                      // fp32 upcast from fp16: low 13 mantissa bits zero
    else {
        const u16* xh = (const u16*)xw;      // 16-bit: fp16 read-as-bf16 shows many tiny magnitudes
        int tiny = 0;
        for (int i = 0; i < 256; ++i) {
            u16 mag = xh[i] & 0x7FFF;
            if (mag != 0 && (mag >> 7) < 118) ++tiny;   // |v| < ~2^-9 as bf16
        }
        mode = (tiny >= 16) ? 2 : 1;
    }
    bool bytes = false;
    for (int i = 0; i < 64; ++i) bytes = bytes || (qw[i] > 255u);
    flags[0] = mode;
    flags[1] = bytes ? 0 : 1;
}

// ---------------- q4_0 decode helpers ----------------
__device__ __forceinline__ void fetch18(const uint8_t* __restrict__ qraw, int qm,
                                        size_t blk, uint32_t b[18]) {
    if (qm == 0) {
        const uint8_t* p = qraw + blk * 18;
        #pragma unroll
        for (int i = 0; i < 18; ++i) b[i] = p[i];
    } else {
        const int* p = (const int*)qraw + blk * 18;
        #pragma unroll
        for (int i = 0; i < 18; ++i) b[i] = ((uint32_t)p[i]) & 0xFFu;
    }
}
__device__ __forceinline__ void decode32(const uint32_t b[18], u16 o[32]) {
    const float d = h2f((u16)(b[0] | (b[1] << 8)));
    #pragma unroll
    for (int i = 0; i < 16; ++i) {
        o[i]      = f2bf(d * (float)((int)(b[2 + i] & 15u) - 8));
        o[16 + i] = f2bf(d * (float)((int)(b[2 + i] >> 4) - 8));
    }
}

__global__ __launch_bounds__(256) void dequant_kernel(const uint8_t* __restrict__ qraw,
                                                      u16* __restrict__ W, int nblocks,
                                                      const int* __restrict__ flags) {
    const int qm = flags[1];
    const int t = blockIdx.x * 256 + threadIdx.x;
    if (t >= nblocks) return;
    uint32_t b[18];
    fetch18(qraw, qm, (size_t)t, b);
    union { u16 h[32]; uint4 v[4]; } o;
    decode32(b, o.h);
    uint4* dst = (uint4*)(W + (size_t)t * 32);
    dst[0] = o.v[0]; dst[1] = o.v[1]; dst[2] = o.v[2]; dst[3] = o.v[3];
}

// ---------------- x -> bf16 conversion ----------------
__global__ __launch_bounds__(256) void convertx_kernel(const void* __restrict__ x,
                                                       u16* __restrict__ X, size_t n8,
                                                       const int* __restrict__ flags) {
    const int mode = flags[0];
    if (mode == 1) return;                   // already bf16, GEMM reads d_in[0] directly
    const size_t t = (size_t)blockIdx.x * 256 + threadIdx.x;
    if (t >= n8) return;
    union { u16 h[8]; uint4 v; } o;
    if (mode == 0) {
        const float4* xf = (const float4*)x;
        float4 a = xf[2 * t], b = xf[2 * t + 1];
        o.h[0] = f2bf(a.x); o.h[1] = f2bf(a.y); o.h[2] = f2bf(a.z); o.h[3] = f2bf(a.w);
        o.h[4] = f2bf(b.x); o.h[5] = f2bf(b.y); o.h[6] = f2bf(b.z); o.h[7] = f2bf(b.w);
    } else {                                 // fp16 bits
        uint4 v = ((const uint4*)x)[t];
        const u16* hh = (const u16*)&v;
        #pragma unroll
        for (int i = 0; i < 8; ++i) o.h[i] = f2bf(h2f(hh[i]));
    }
    ((uint4*)X)[t] = o.v;
}

// ---------------- epilogue helpers ----------------
__device__ __forceinline__ float load_bias(const void* bias, int col, int mode) {
    if (mode == 0) return ((const float*)bias)[col];
    u16 b = ((const u16*)bias)[col];
    return (mode == 1) ? bf2f(b) : h2f(b);
}
__device__ __forceinline__ void store_out(void* out, size_t idx, float v, int mode) {
    if (mode == 0)      ((float*)out)[idx] = v;
    else if (mode == 1) ((u16*)out)[idx] = f2bf(v);
    else                ((u16*)out)[idx] = f2h(v);
}

// ---------------- main GEMM (ws path): A,B bf16, global_load_lds staging ----------------
__global__ __launch_bounds__(256) void gemm_main(const u16* __restrict__ Xraw,
                                                 const u16* __restrict__ Xconv,
                                                 const u16* __restrict__ W,
                                                 const void* __restrict__ bias,
                                                 void* __restrict__ out,
                                                 const int* __restrict__ flags,
                                                 int M, int N, int K) {
    __shared__ __align__(16) u16 lA[BM * BK];
    __shared__ __align__(16) u16 lB[BN * BK];

    const int mode = flags[0];
    const u16* A = (mode == 1) ? Xraw : Xconv;

    const int tid  = threadIdx.x;
    const int lane = tid & 63;
    const int wid  = tid >> 6;
    const int gn   = N / BN;

    const int b   = blockIdx.x;
    const int per = gridDim.x >> 3;
    const int sw  = ((per << 3) == (int)gridDim.x) ? ((b & 7) * per + (b >> 3)) : b;
    const int m0  = (sw / gn) * BM;
    const int n0  = (sw % gn) * BN;

    const int wm = wid >> 1, wn = wid & 1;
    const int srow = lane >> 3;
    const int scol = (lane & 7) * 16;
    const int lm = lane & 15;
    const int kg = lane >> 4;

    f32x4 acc[4][4] = {};

    for (int k0 = 0; k0 < K; k0 += BK) {
        #pragma unroll
        for (int it = 0; it < 4; ++it) {
            const int r0 = wid * 32 + it * 8;
            const char* ga = (const char*)A + ((size_t)(m0 + r0 + srow) * K + k0) * 2 + scol;
            __builtin_amdgcn_global_load_lds(
                (const __attribute__((address_space(1))) uint32_t*)ga,
                (__attribute__((address_space(3))) uint32_t*)((char*)lA + r0 * (BK * 2)),
                16, 0, 0);
        }
        #pragma unroll
        for (int it = 0; it < 4; ++it) {
            const int r0 = wid * 32 + it * 8;
            const char* gb = (const char*)W + ((size_t)(n0 + r0 + srow) * K + k0) * 2 + scol;
            __builtin_amdgcn_global_load_lds(
                (const __attribute__((address_space(1))) uint32_t*)gb,
                (__attribute__((address_space(3))) uint32_t*)((char*)lB + r0 * (BK * 2)),
                16, 0, 0);
        }
        __syncthreads();

        #pragma unroll
        for (int kk = 0; kk < 2; ++kk) {
            bf16x8 av[4], bv[4];
            #pragma unroll
            for (int i = 0; i < 4; ++i) {
                av[i] = *(const bf16x8*)&lA[(wm * 64 + i * 16 + lm) * BK + kk * 32 + kg * 8];
                bv[i] = *(const bf16x8*)&lB[(wn * 64 + i * 16 + lm) * BK + kk * 32 + kg * 8];
            }
            #pragma unroll
            for (int i = 0; i < 4; ++i)
                #pragma unroll
                for (int j = 0; j < 4; ++j)
                    acc[i][j] = __builtin_amdgcn_mfma_f32_16x16x32_bf16(av[i], bv[j], acc[i][j], 0, 0, 0);
        }
        __syncthreads();
    }

    const int rg = (lane >> 4) * 4;
    #pragma unroll
    for (int j = 0; j < 4; ++j) {
        const int col = n0 + wn * 64 + j * 16 + lm;
        const float bvf = load_bias(bias, col, mode);
        #pragma unroll
        for (int i = 0; i < 4; ++i) {
            const int row = m0 + wm * 64 + i * 16 + rg;
            #pragma unroll
            for (int r = 0; r < 4; ++r)
                store_out(out, (size_t)(row + r) * N + col, acc[i][j][r] + bvf, mode);
        }
    }
}

// ---------------- fallback GEMM (tiny ws): fully fused ----------------
__global__ __launch_bounds__(256) void gemm_fallback(const void* __restrict__ x,
                                                     const uint8_t* __restrict__ qraw,
                                                     const void* __restrict__ bias,
                                                     void* __restrict__ out,
                                                     const int* __restrict__ flags,
                                                     int M, int N, int K, int has_flags) {
    __shared__ __align__(16) u16 lA[BM * BK];
    __shared__ __align__(16) u16 lB[BN * BK];

    const int mode = has_flags ? flags[0] : 0;
    const int qm   = has_flags ? flags[1] : 0;

    const int tid  = threadIdx.x;
    const int lane = tid & 63;
    const int wid  = tid >> 6;
    const int gn   = N / BN;

    const int b   = blockIdx.x;
    const int per = gridDim.x >> 3;
    const int sw  = ((per << 3) == (int)gridDim.x) ? ((b & 7) * per + (b >> 3)) : b;
    const int m0  = (sw / gn) * BM;
    const int n0  = (sw % gn) * BN;

    const int wm = wid >> 1, wn = wid & 1;
    const int lm = lane & 15;
    const int kg = lane >> 4;
    const int rowQ = tid >> 1, halfQ = tid & 1;

    f32x4 acc[4][4] = {};

    for (int k0 = 0; k0 < K; k0 += BK) {
        // A: reg-stage + convert -> LDS
        #pragma unroll
        for (int rep = 0; rep < 4; ++rep) {
            const int c = rep * 256 + tid;          // 1024 chunks of 8 elems
            const int row = c >> 3, col = (c & 7) * 8;
            union { u16 h[8]; uint4 v; } o;
            if (mode == 0) {
                const float4* xf = (const float4*)x + ((size_t)(m0 + row) * K + k0 + col) / 4;
                float4 a = xf[0], b2 = xf[1];
                o.h[0] = f2bf(a.x);  o.h[1] = f2bf(a.y);  o.h[2] = f2bf(a.z);  o.h[3] = f2bf(a.w);
                o.h[4] = f2bf(b2.x); o.h[5] = f2bf(b2.y); o.h[6] = f2bf(b2.z); o.h[7] = f2bf(b2.w);
            } else {
                uint4 v = *(const uint4*)((const u16*)x + (size_t)(m0 + row) * K + k0 + col);
                if (mode == 1) o.v = v;
                else {
                    const u16* hh = (const u16*)&v;
                    #pragma unroll
                    for (int i = 0; i < 8; ++i) o.h[i] = f2bf(h2f(hh[i]));
                }
            }
            *(uint4*)&lA[row * BK + col] = o.v;
        }
        // B: fused dequant -> LDS
        {
            const size_t blk = (size_t)(n0 + rowQ) * (K >> 5) + (k0 >> 5) + halfQ;
            uint32_t bb[18];
            fetch18(qraw, qm, blk, bb);
            union { u16 h[32]; uint4 v[4]; } o;
            decode32(bb, o.h);
            uint4* dst = (uint4*)&lB[rowQ * BK + halfQ * 32];
            dst[0] = o.v[0]; dst[1] = o.v[1]; dst[2] = o.v[2]; dst[3] = o.v[3];
        }
        __syncthreads();

        #pragma unroll
        for (int kk = 0; kk < 2; ++kk) {
            bf16x8 av[4], bv[4];
            #pragma unroll
            for (int i = 0; i < 4; ++i) {
                av[i] = *(const bf16x8*)&lA[(wm * 64 + i * 16 + lm) * BK + kk * 32 + kg * 8];
                bv[i] = *(const bf16x8*)&lB[(wn * 64 + i * 16 + lm) * BK + kk * 32 + kg * 8];
            }
            #pragma unroll
            for (int i = 0; i < 4; ++i)
                #pragma unroll
                for (int j = 0; j < 4; ++j)
                    acc[i][j] = __builtin_amdgcn_mfma_f32_16x16x32_bf16(av[i], bv[j], acc[i][j], 0, 0, 0);
        }
        __syncthreads();
    }

    const int rg = (lane >> 4) * 4;
    #pragma unroll
    for (int j = 0; j < 4; ++j) {
        const int col = n0 + wn * 64 + j * 16 + lm;
        const float bvf = load_bias(bias, col, mode);
        #pragma unroll
        for (int i = 0; i < 4; ++i) {
            const int row = m0 + wm * 64 + i * 16 + rg;
            #pragma unroll
            for (int r = 0; r < 4; ++r)
                store_out(out, (size_t)(row + r) * N + col, acc[i][j][r] + bvf, mode);
        }
    }
}

extern "C" void kernel_launch(void* const* d_in, const int* in_sizes, int n_in,
                              void* d_out, int out_size, void* d_ws, size_t ws_size,
                              hipStream_t stream) {
    const void*    x    = d_in[0];
    const uint8_t* qw   = (const uint8_t*)d_in[1];
    const void*    bias = d_in[2];

    const int N = in_sizes[2];                 // 4096
    const int row_elems = in_sizes[1] / N;     // 2304
    const int K = (row_elems / 18) * 32;       // 4096
    const int M = in_sizes[0] / K;             // 8192

    dim3 blk(256);
    const int nwg = (M / BM) * (N / BN);       // 2048

    const size_t offW = 256;
    const size_t offX = offW + (size_t)N * K * 2;
    const size_t need = offX + (size_t)M * K * 2;   // ~96 MB

    if (ws_size >= need) {
        int* flags = (int*)d_ws;
        u16* W = (u16*)((char*)d_ws + offW);
        u16* X = (u16*)((char*)d_ws + offX);
        detect_kernel<<<1, 64, 0, stream>>>((const uint32_t*)x, (const uint32_t*)qw, flags);
        const int nblocks = N * (K >> 5);
        dequant_kernel<<<(nblocks + 255) / 256, 256, 0, stream>>>(qw, W, nblocks, flags);
        const size_t n8 = (size_t)M * K / 8;
        convertx_kernel<<<(int)((n8 + 255) / 256), 256, 0, stream>>>(x, X, n8, flags);
        gemm_main<<<nwg, blk, 0, stream>>>((const u16*)x, X, W, bias, d_out, flags, M, N, K);
    } else if (ws_size >= 16) {
        int* flags = (int*)d_ws;
        detect_kernel<<<1, 64, 0, stream>>>((const uint32_t*)x, (const uint32_t*)qw, flags);
        gemm_fallback<<<nwg, blk, 0, stream>>>(x, qw, bias, d_out, flags, M, N, K, 1);
    } else {
        gemm_fallback<<<nwg, blk, 0, stream>>>(x, qw, bias, d_out, nullptr, M, N, K, 0);
    }
}

// Round 3
// 325.410 us; speedup vs baseline: 1.4087x; 1.4087x over previous
//
#include <hip/hip_runtime.h>
#include <stdint.h>

typedef unsigned short u16;
typedef __attribute__((ext_vector_type(8))) __bf16 bf16x8;
typedef __attribute__((ext_vector_type(4))) float f32x4;

// ---------------- scalar helpers ----------------
__device__ __forceinline__ u16 f2bf(float f) {
    uint32_t u = __float_as_uint(f);
    u += 0x7FFF + ((u >> 16) & 1);   // RNE
    return (u16)(u >> 16);
}
__device__ __forceinline__ float bf2f(u16 b) {
    return __uint_as_float(((uint32_t)b) << 16);
}
__device__ __forceinline__ float h2f(u16 h) {
    float r; uint32_t x = h;
    asm volatile("v_cvt_f32_f16_e32 %0, %1" : "=v"(r) : "v"(x));
    return r;
}
__device__ __forceinline__ u16 f2h(float f) {
    uint32_t r;
    asm volatile("v_cvt_f16_f32_e32 %0, %1" : "=v"(r) : "v"(f));
    return (u16)r;
}

// ---------------- dtype detection ----------------
// flags[0]: x/bias/out mode: 0=float32, 1=bf16(u16), 2=fp16(u16)
// flags[1]: qweight mode:    0=packed bytes, 1=one byte per int32
__global__ void detect_kernel(const uint32_t* __restrict__ xw,
                              const uint32_t* __restrict__ qw,
                              int* __restrict__ flags) {
    if (blockIdx.x | threadIdx.x) return;
    bool allz = true;
    for (int i = 0; i < 64; ++i) allz = allz && ((xw[i] & 0x1FFFu) == 0u);
    int mode;
    if (allz) mode = 0;
    else {
        const u16* xh = (const u16*)xw;
        int tiny = 0;
        for (int i = 0; i < 256; ++i) {
            u16 mag = xh[i] & 0x7FFF;
            if (mag != 0 && (mag >> 7) < 118) ++tiny;
        }
        mode = (tiny >= 16) ? 2 : 1;
    }
    bool bytes = false;
    for (int i = 0; i < 64; ++i) bytes = bytes || (qw[i] > 255u);
    flags[0] = mode;
    flags[1] = bytes ? 0 : 1;
}

// ---------------- q4_0 decode ----------------
__device__ __forceinline__ void fetch18(const uint8_t* __restrict__ qraw, int qm,
                                        size_t blk, uint32_t b[18]) {
    if (qm == 0) {
        const uint8_t* p = qraw + blk * 18;
        #pragma unroll
        for (int i = 0; i < 18; ++i) b[i] = p[i];
    } else {
        const int* p = (const int*)qraw + blk * 18;
        #pragma unroll
        for (int i = 0; i < 18; ++i) b[i] = ((uint32_t)p[i]) & 0xFFu;
    }
}
__device__ __forceinline__ void decode32(const uint32_t b[18], u16 o[32]) {
    const float d = h2f((u16)(b[0] | (b[1] << 8)));
    #pragma unroll
    for (int i = 0; i < 16; ++i) {
        o[i]      = f2bf(d * (float)((int)(b[2 + i] & 15u) - 8));
        o[16 + i] = f2bf(d * (float)((int)(b[2 + i] >> 4) - 8));
    }
}

__global__ __launch_bounds__(256) void dequant_kernel(const uint8_t* __restrict__ qraw,
                                                      u16* __restrict__ W, int nblocks,
                                                      const int* __restrict__ flags) {
    const int qm = flags[1];
    const int t = blockIdx.x * 256 + threadIdx.x;
    if (t >= nblocks) return;
    uint32_t b[18];
    fetch18(qraw, qm, (size_t)t, b);
    union { u16 h[32]; uint4 v[4]; } o;
    decode32(b, o.h);
    uint4* dst = (uint4*)(W + (size_t)t * 32);
    dst[0] = o.v[0]; dst[1] = o.v[1]; dst[2] = o.v[2]; dst[3] = o.v[3];
}

// ---------------- x -> bf16 ----------------
__global__ __launch_bounds__(256) void convertx_kernel(const void* __restrict__ x,
                                                       u16* __restrict__ X, size_t n8,
                                                       const int* __restrict__ flags) {
    const int mode = flags[0];
    if (mode == 1) return;
    const size_t t = (size_t)blockIdx.x * 256 + threadIdx.x;
    if (t >= n8) return;
    union { u16 h[8]; uint4 v; } o;
    if (mode == 0) {
        const float4* xf = (const float4*)x;
        float4 a = xf[2 * t], b = xf[2 * t + 1];
        o.h[0] = f2bf(a.x); o.h[1] = f2bf(a.y); o.h[2] = f2bf(a.z); o.h[3] = f2bf(a.w);
        o.h[4] = f2bf(b.x); o.h[5] = f2bf(b.y); o.h[6] = f2bf(b.z); o.h[7] = f2bf(b.w);
    } else {
        uint4 v = ((const uint4*)x)[t];
        const u16* hh = (const u16*)&v;
        #pragma unroll
        for (int i = 0; i < 8; ++i) o.h[i] = f2bf(h2f(hh[i]));
    }
    ((uint4*)X)[t] = o.v;
}

// ---------------- epilogue helpers ----------------
__device__ __forceinline__ float load_bias(const void* bias, int col, int mode) {
    if (mode == 0) return ((const float*)bias)[col];
    u16 b = ((const u16*)bias)[col];
    return (mode == 1) ? bf2f(b) : h2f(b);
}
__device__ __forceinline__ void store_out(void* out, size_t idx, float v, int mode) {
    if (mode == 0)      ((float*)out)[idx] = v;
    else if (mode == 1) ((u16*)out)[idx] = f2bf(v);
    else                ((u16*)out)[idx] = f2h(v);
}

// ---------------- 256x256 8-phase GEMM ----------------
// LDS (u16 units): A(buf,half) at (buf*2+half)*8192 ; B at 32768 + (buf*2+half)*8192
// half = 128 rows x 64 cols bf16. Total 128 KiB.
// Stage: 2 x global_load_lds dwordx4 per thread per half-tile; LDS dest linear,
// global source pre-swizzled (col ^= 16 elems when lane&32) so that readers
// using  col ^= 16 when (row&4)  see a bank-spread layout (st_16x32 involution).
__device__ __forceinline__ void stage_half(const u16* __restrict__ G, int row0, int k0,
                                           int kstride, u16* dstreg, int tid) {
    const int l = tid & 63, w = tid >> 6;
    const int r = w * 8 + (l >> 3);
    const int c = ((l & 7) * 8) ^ ((l & 32) >> 1);   // ^16 elems when l>=32
    #pragma unroll
    for (int ch = 0; ch < 2; ++ch) {
        const u16* src = G + (size_t)(row0 + ch * 64 + r) * kstride + (k0 + c);
        u16* dst = dstreg + ch * 4096 + w * 512;     // wave-uniform; HW adds lane*16B
        __builtin_amdgcn_global_load_lds(
            (const __attribute__((address_space(1))) uint32_t*)src,
            (__attribute__((address_space(3))) uint32_t*)dst, 16, 0, 0);
    }
}

#define PH_MID  __builtin_amdgcn_s_barrier();                 \
                asm volatile("s_waitcnt lgkmcnt(0)");         \
                __builtin_amdgcn_sched_barrier(0);            \
                __builtin_amdgcn_s_setprio(1);

#define PH_END  __builtin_amdgcn_s_setprio(0);                \
                __builtin_amdgcn_s_barrier();                 \
                __builtin_amdgcn_sched_barrier(0);

#define RD_A(HM)                                                                   \
    _Pragma("unroll")                                                              \
    for (int i = 0; i < 4; ++i) {                                                  \
        ra[i][0] = *(const bf16x8*)&lds[aB + ((HM)*64 + i*16 + lm)*64 + cc0];      \
        ra[i][1] = *(const bf16x8*)&lds[aB + ((HM)*64 + i*16 + lm)*64 + cc1];      \
    }

#define RD_B(HN, RB)                                                               \
    _Pragma("unroll")                                                              \
    for (int j = 0; j < 2; ++j) {                                                  \
        RB[j][0] = *(const bf16x8*)&lds[bB + (bh + (HN)*32 + j*16 + lm)*64 + cc0]; \
        RB[j][1] = *(const bf16x8*)&lds[bB + (bh + (HN)*32 + j*16 + lm)*64 + cc1]; \
    }

#define MFMA_Q(HM, HN, RB)                                                         \
    _Pragma("unroll")                                                              \
    for (int i = 0; i < 4; ++i)                                                    \
        _Pragma("unroll")                                                          \
        for (int j = 0; j < 2; ++j) {                                              \
            acc[(HM)*4+i][(HN)*2+j] = __builtin_amdgcn_mfma_f32_16x16x32_bf16(     \
                ra[i][0], RB[j][0], acc[(HM)*4+i][(HN)*2+j], 0, 0, 0);             \
            acc[(HM)*4+i][(HN)*2+j] = __builtin_amdgcn_mfma_f32_16x16x32_bf16(     \
                ra[i][1], RB[j][1], acc[(HM)*4+i][(HN)*2+j], 0, 0, 0);             \
        }

// tile t (buffer BUF): phases read quadrants (0,0),(0,1),(1,0),(1,1);
// stages: ph0 -> A1(t+1) [other buf], ph2 -> B0(t+2), ph3 -> B1(t+2)+A0(t+2) [this buf]
#define KTILE(TT, BUF)                                                             \
    {                                                                              \
        const int kt1 = ((TT)+1 < nt ? (TT)+1 : nt-1) * 64;                        \
        const int kt2 = ((TT)+2 < nt ? (TT)+2 : nt-1) * 64;                        \
        const int aB = ((BUF)*2 + wm) * 8192;                                      \
        const int bB = 32768 + ((BUF)*2 + (wn >> 1)) * 8192;                       \
        /* phase 0 */                                                              \
        RD_A(0) RD_B(0, rb0)                                                       \
        stage_half(Aptr, m0 + 128, kt1, K, lds + ((((BUF)^1)*2 + 1) * 8192), tid); \
        PH_MID  MFMA_Q(0, 0, rb0)  PH_END                                          \
        /* phase 1 */                                                              \
        RD_B(1, rb1)                                                               \
        PH_MID  MFMA_Q(0, 1, rb1)  PH_END                                          \
        /* phase 2 */                                                              \
        RD_A(1)                                                                    \
        stage_half(Wptr, n0, kt2, K, lds + (32768 + ((BUF)*2) * 8192), tid);       \
        PH_MID  MFMA_Q(1, 0, rb0)  PH_END                                          \
        /* phase 3 */                                                              \
        stage_half(Wptr, n0 + 128, kt2, K, lds + (32768 + ((BUF)*2+1) * 8192), tid); \
        stage_half(Aptr, m0,       kt2, K, lds + (((BUF)*2) * 8192), tid);         \
        PH_MID  MFMA_Q(1, 1, rb1)                                                  \
        __builtin_amdgcn_s_setprio(0);                                             \
        asm volatile("s_waitcnt vmcnt(6)");                                        \
        __builtin_amdgcn_s_barrier();                                              \
        __builtin_amdgcn_sched_barrier(0);                                         \
    }

__global__ __launch_bounds__(512) void gemm_8ph(const u16* __restrict__ Xraw,
                                                const u16* __restrict__ Xconv,
                                                const u16* __restrict__ Wmat,
                                                const void* __restrict__ bias,
                                                void* __restrict__ out,
                                                const int* __restrict__ flags,
                                                int M, int N, int K) {
    __shared__ __align__(16) u16 lds[65536];   // 128 KiB

    const int mode = flags[0];
    const u16* Aptr = (mode == 1) ? Xraw : Xconv;
    const u16* Wptr = Wmat;

    const int tid  = threadIdx.x;
    const int lane = tid & 63;
    const int wid  = tid >> 6;
    const int wm   = wid >> 2;        // 0..1 (M)
    const int wn   = wid & 3;         // 0..3 (N)
    const int lm   = lane & 15;
    const int kg   = lane >> 4;
    const int bh   = (wn & 1) * 64;
    const int swzu = (lm & 4) << 2;               // ^16 u16 when row&4
    const int cc0  = (kg * 8) ^ swzu;
    const int cc1  = (32 + kg * 8) ^ swzu;

    const int gn = N / 256;
    const int b  = blockIdx.x;
    const int per = gridDim.x >> 3;
    const int sw = ((per << 3) == (int)gridDim.x) ? ((b & 7) * per + (b >> 3)) : b;
    const int m0 = (sw / gn) * 256;
    const int n0 = (sw % gn) * 256;

    const int nt = K >> 6;

    bf16x8 ra[4][2];
    bf16x8 rb0[2][2], rb1[2][2];
    f32x4 acc[8][4] = {};

    // prologue: tile0 fully (A0,A1,B0,B1) + tile1 (A0,B0,B1); tile1.A1 staged at ph0 of tile0
    stage_half(Aptr, m0,       0,  K, lds + 0,             tid);
    stage_half(Aptr, m0 + 128, 0,  K, lds + 8192,          tid);
    stage_half(Wptr, n0,       0,  K, lds + 32768,         tid);
    stage_half(Wptr, n0 + 128, 0,  K, lds + 32768 + 8192,  tid);
    stage_half(Aptr, m0,       64, K, lds + 2 * 8192,      tid);
    stage_half(Wptr, n0,       64, K, lds + 32768 + 2 * 8192, tid);
    stage_half(Wptr, n0 + 128, 64, K, lds + 32768 + 3 * 8192, tid);
    asm volatile("s_waitcnt vmcnt(6)");
    __builtin_amdgcn_s_barrier();
    __builtin_amdgcn_sched_barrier(0);

    for (int t = 0; t < nt; t += 2) {
        KTILE(t, 0)
        KTILE(t + 1, 1)
    }

    // epilogue
    const int rr4 = (lane >> 4) * 4;
    #pragma unroll
    for (int j = 0; j < 4; ++j) {
        const int col = n0 + wn * 64 + j * 16 + lm;
        const float bvf = load_bias(bias, col, mode);
        #pragma unroll
        for (int i = 0; i < 8; ++i) {
            const int row = m0 + wm * 128 + i * 16 + rr4;
            #pragma unroll
            for (int r = 0; r < 4; ++r)
                store_out(out, (size_t)(row + r) * N + col, acc[i][j][r] + bvf, mode);
        }
    }
}

// ---------------- fallback (tiny ws): fused 128-tile ----------------
__global__ __launch_bounds__(256) void gemm_fallback(const void* __restrict__ x,
                                                     const uint8_t* __restrict__ qraw,
                                                     const void* __restrict__ bias,
                                                     void* __restrict__ out,
                                                     const int* __restrict__ flags,
                                                     int M, int N, int K, int has_flags) {
    __shared__ __align__(16) u16 lA[128 * 64];
    __shared__ __align__(16) u16 lB[128 * 64];

    const int mode = has_flags ? flags[0] : 0;
    const int qm   = has_flags ? flags[1] : 0;

    const int tid  = threadIdx.x;
    const int lane = tid & 63;
    const int wid  = tid >> 6;
    const int gn   = N / 128;

    const int b   = blockIdx.x;
    const int per = gridDim.x >> 3;
    const int sw  = ((per << 3) == (int)gridDim.x) ? ((b & 7) * per + (b >> 3)) : b;
    const int m0  = (sw / gn) * 128;
    const int n0  = (sw % gn) * 128;

    const int wm = wid >> 1, wn = wid & 1;
    const int lm = lane & 15;
    const int kg = lane >> 4;
    const int rowQ = tid >> 1, halfQ = tid & 1;

    f32x4 acc[4][4] = {};

    for (int k0 = 0; k0 < K; k0 += 64) {
        #pragma unroll
        for (int rep = 0; rep < 4; ++rep) {
            const int c = rep * 256 + tid;
            const int row = c >> 3, col = (c & 7) * 8;
            union { u16 h[8]; uint4 v; } o;
            if (mode == 0) {
                const float4* xf = (const float4*)x + ((size_t)(m0 + row) * K + k0 + col) / 4;
                float4 a = xf[0], b2 = xf[1];
                o.h[0] = f2bf(a.x);  o.h[1] = f2bf(a.y);  o.h[2] = f2bf(a.z);  o.h[3] = f2bf(a.w);
                o.h[4] = f2bf(b2.x); o.h[5] = f2bf(b2.y); o.h[6] = f2bf(b2.z); o.h[7] = f2bf(b2.w);
            } else {
                uint4 v = *(const uint4*)((const u16*)x + (size_t)(m0 + row) * K + k0 + col);
                if (mode == 1) o.v = v;
                else {
                    const u16* hh = (const u16*)&v;
                    #pragma unroll
                    for (int i = 0; i < 8; ++i) o.h[i] = f2bf(h2f(hh[i]));
                }
            }
            *(uint4*)&lA[row * 64 + col] = o.v;
        }
        {
            const size_t blk = (size_t)(n0 + rowQ) * (K >> 5) + (k0 >> 5) + halfQ;
            uint32_t bb[18];
            fetch18(qraw, qm, blk, bb);
            union { u16 h[32]; uint4 v[4]; } o;
            decode32(bb, o.h);
            uint4* dst = (uint4*)&lB[rowQ * 64 + halfQ * 32];
            dst[0] = o.v[0]; dst[1] = o.v[1]; dst[2] = o.v[2]; dst[3] = o.v[3];
        }
        __syncthreads();

        #pragma unroll
        for (int kk = 0; kk < 2; ++kk) {
            bf16x8 av[4], bv[4];
            #pragma unroll
            for (int i = 0; i < 4; ++i) {
                av[i] = *(const bf16x8*)&lA[(wm * 64 + i * 16 + lm) * 64 + kk * 32 + kg * 8];
                bv[i] = *(const bf16x8*)&lB[(wn * 64 + i * 16 + lm) * 64 + kk * 32 + kg * 8];
            }
            #pragma unroll
            for (int i = 0; i < 4; ++i)
                #pragma unroll
                for (int j = 0; j < 4; ++j)
                    acc[i][j] = __builtin_amdgcn_mfma_f32_16x16x32_bf16(av[i], bv[j], acc[i][j], 0, 0, 0);
        }
        __syncthreads();
    }

    const int rg = (lane >> 4) * 4;
    #pragma unroll
    for (int j = 0; j < 4; ++j) {
        const int col = n0 + wn * 64 + j * 16 + lm;
        const float bvf = load_bias(bias, col, mode);
        #pragma unroll
        for (int i = 0; i < 4; ++i) {
            const int row = m0 + wm * 64 + i * 16 + rg;
            #pragma unroll
            for (int r = 0; r < 4; ++r)
                store_out(out, (size_t)(row + r) * N + col, acc[i][j][r] + bvf, mode);
        }
    }
}

extern "C" void kernel_launch(void* const* d_in, const int* in_sizes, int n_in,
                              void* d_out, int out_size, void* d_ws, size_t ws_size,
                              hipStream_t stream) {
    const void*    x    = d_in[0];
    const uint8_t* qw   = (const uint8_t*)d_in[1];
    const void*    bias = d_in[2];

    const int N = in_sizes[2];
    const int row_elems = in_sizes[1] / N;
    const int K = (row_elems / 18) * 32;
    const int M = in_sizes[0] / K;

    const size_t offW = 256;
    const size_t offX = offW + (size_t)N * K * 2;
    const size_t need = offX + (size_t)M * K * 2;

    const int nt = K >> 6;
    const bool big_ok = (M % 256 == 0) && (N % 256 == 0) && (nt >= 4) && ((nt & 1) == 0);

    if (ws_size >= need && big_ok) {
        int* flags = (int*)d_ws;
        u16* W = (u16*)((char*)d_ws + offW);
        u16* X = (u16*)((char*)d_ws + offX);
        detect_kernel<<<1, 64, 0, stream>>>((const uint32_t*)x, (const uint32_t*)qw, flags);
        const int nblocks = N * (K >> 5);
        dequant_kernel<<<(nblocks + 255) / 256, 256, 0, stream>>>(qw, W, nblocks, flags);
        const size_t n8 = (size_t)M * K / 8;
        convertx_kernel<<<(int)((n8 + 255) / 256), 256, 0, stream>>>(x, X, n8, flags);
        gemm_8ph<<<(M / 256) * (N / 256), 512, 0, stream>>>((const u16*)x, X, W, bias,
                                                            d_out, flags, M, N, K);
    } else if (ws_size >= 16) {
        int* flags = (int*)d_ws;
        detect_kernel<<<1, 64, 0, stream>>>((const uint32_t*)x, (const uint32_t*)qw, flags);
        gemm_fallback<<<(M / 128) * (N / 128), 256, 0, stream>>>(x, qw, bias, d_out, flags, M, N, K, 1);
    } else {
        gemm_fallback<<<(M / 128) * (N / 128), 256, 0, stream>>>(x, qw, bias, d_out, nullptr, M, N, K, 0);
    }
}

// Round 4
// 301.779 us; speedup vs baseline: 1.5190x; 1.0783x over previous
//
#include <hip/hip_runtime.h>
#include <stdint.h>

typedef unsigned short u16;
typedef __attribute__((ext_vector_type(8))) __bf16 bf16x8;
typedef __attribute__((ext_vector_type(4))) float f32x4;

// ---------------- scalar helpers ----------------
__device__ __forceinline__ u16 f2bf(float f) {
    uint32_t u = __float_as_uint(f);
    u += 0x7FFF + ((u >> 16) & 1);   // RNE
    return (u16)(u >> 16);
}
__device__ __forceinline__ float bf2f(u16 b) {
    return __uint_as_float(((uint32_t)b) << 16);
}
__device__ __forceinline__ float h2f(u16 h) {
    float r; uint32_t x = h;
    asm volatile("v_cvt_f32_f16_e32 %0, %1" : "=v"(r) : "v"(x));
    return r;
}
__device__ __forceinline__ u16 f2h(float f) {
    uint32_t r;
    asm volatile("v_cvt_f16_f32_e32 %0, %1" : "=v"(r) : "v"(f));
    return (u16)r;
}

// ---------------- dtype detection ----------------
// flags[0]: x/bias/out mode: 0=float32, 1=bf16(u16), 2=fp16(u16)
// flags[1]: qweight mode:    0=packed bytes, 1=one byte per int32
__global__ void detect_kernel(const uint32_t* __restrict__ xw,
                              const uint32_t* __restrict__ qw,
                              int* __restrict__ flags) {
    if (blockIdx.x | threadIdx.x) return;
    bool allz = true;
    for (int i = 0; i < 64; ++i) allz = allz && ((xw[i] & 0x1FFFu) == 0u);
    int mode;
    if (allz) mode = 0;
    else {
        const u16* xh = (const u16*)xw;
        int tiny = 0;
        for (int i = 0; i < 256; ++i) {
            u16 mag = xh[i] & 0x7FFF;
            if (mag != 0 && (mag >> 7) < 118) ++tiny;
        }
        mode = (tiny >= 16) ? 2 : 1;
    }
    bool bytes = false;
    for (int i = 0; i < 64; ++i) bytes = bytes || (qw[i] > 255u);
    flags[0] = mode;
    flags[1] = bytes ? 0 : 1;
}

// ---------------- q4_0 decode ----------------
__device__ __forceinline__ void fetch18(const uint8_t* __restrict__ qraw, int qm,
                                        size_t blk, uint32_t b[18]) {
    if (qm == 0) {
        const uint8_t* p = qraw + blk * 18;
        #pragma unroll
        for (int i = 0; i < 18; ++i) b[i] = p[i];
    } else {
        const int* p = (const int*)qraw + blk * 18;
        #pragma unroll
        for (int i = 0; i < 18; ++i) b[i] = ((uint32_t)p[i]) & 0xFFu;
    }
}
__device__ __forceinline__ void decode32(const uint32_t b[18], u16 o[32]) {
    const float d = h2f((u16)(b[0] | (b[1] << 8)));
    #pragma unroll
    for (int i = 0; i < 16; ++i) {
        o[i]      = f2bf(d * (float)((int)(b[2 + i] & 15u) - 8));
        o[16 + i] = f2bf(d * (float)((int)(b[2 + i] >> 4) - 8));
    }
}

__global__ __launch_bounds__(256) void dequant_kernel(const uint8_t* __restrict__ qraw,
                                                      u16* __restrict__ W, int nblocks,
                                                      const int* __restrict__ flags) {
    const int qm = flags[1];
    const int t = blockIdx.x * 256 + threadIdx.x;
    if (t >= nblocks) return;
    uint32_t b[18];
    fetch18(qraw, qm, (size_t)t, b);
    union { u16 h[32]; uint4 v[4]; } o;
    decode32(b, o.h);
    uint4* dst = (uint4*)(W + (size_t)t * 32);
    dst[0] = o.v[0]; dst[1] = o.v[1]; dst[2] = o.v[2]; dst[3] = o.v[3];
}

// ---------------- x -> bf16 ----------------
__global__ __launch_bounds__(256) void convertx_kernel(const void* __restrict__ x,
                                                       u16* __restrict__ X, size_t n8,
                                                       const int* __restrict__ flags) {
    const int mode = flags[0];
    if (mode == 1) return;
    const size_t t = (size_t)blockIdx.x * 256 + threadIdx.x;
    if (t >= n8) return;
    union { u16 h[8]; uint4 v; } o;
    if (mode == 0) {
        const float4* xf = (const float4*)x;
        float4 a = xf[2 * t], b = xf[2 * t + 1];
        o.h[0] = f2bf(a.x); o.h[1] = f2bf(a.y); o.h[2] = f2bf(a.z); o.h[3] = f2bf(a.w);
        o.h[4] = f2bf(b.x); o.h[5] = f2bf(b.y); o.h[6] = f2bf(b.z); o.h[7] = f2bf(b.w);
    } else {
        uint4 v = ((const uint4*)x)[t];
        const u16* hh = (const u16*)&v;
        #pragma unroll
        for (int i = 0; i < 8; ++i) o.h[i] = f2bf(h2f(hh[i]));
    }
    ((uint4*)X)[t] = o.v;
}

// ---------------- epilogue helpers ----------------
__device__ __forceinline__ float load_bias(const void* bias, int col, int mode) {
    if (mode == 0) return ((const float*)bias)[col];
    u16 b = ((const u16*)bias)[col];
    return (mode == 1) ? bf2f(b) : h2f(b);
}
__device__ __forceinline__ void store_out(void* out, size_t idx, float v, int mode) {
    if (mode == 0)      ((float*)out)[idx] = v;
    else if (mode == 1) ((u16*)out)[idx] = f2bf(v);
    else                ((u16*)out)[idx] = f2h(v);
}

// ---------------- 256x256 8-phase GEMM ----------------
// LDS (u16 units): A(buf,half) at (buf*2+half)*8192 ; B at 32768 + (buf*2+half)*8192
// half = 128 rows x 64 cols bf16. Total 128 KiB.
// Swizzle (both-sides involution, G4 formula): LDS[row][col] holds
// G[grow][col ^ 8*(row&7)]. Readers XOR the same key -> bank-slot
// kg ^ (lm&7): exact 8-way uniform, conflict-free ds_read_b128.
__device__ __forceinline__ void stage_half(const u16* __restrict__ G, int row0, int k0,
                                           int kstride, u16* dstreg, int tid) {
    const int l = tid & 63, w = tid >> 6;
    const int r = w * 8 + (l >> 3);
    const int c = ((l & 7) * 8) ^ (((l >> 3) & 7) * 8);   // col ^ 8*(row&7)
    #pragma unroll
    for (int ch = 0; ch < 2; ++ch) {
        const u16* src = G + (size_t)(row0 + ch * 64 + r) * kstride + (k0 + c);
        u16* dst = dstreg + ch * 4096 + w * 512;     // wave-uniform; HW adds lane*16B
        __builtin_amdgcn_global_load_lds(
            (const __attribute__((address_space(1))) uint32_t*)src,
            (__attribute__((address_space(3))) uint32_t*)dst, 16, 0, 0);
    }
}

#define PH_MID  __builtin_amdgcn_s_barrier();                 \
                asm volatile("s_waitcnt lgkmcnt(0)");         \
                __builtin_amdgcn_sched_barrier(0);            \
                __builtin_amdgcn_s_setprio(1);

#define PH_END  __builtin_amdgcn_s_setprio(0);                \
                __builtin_amdgcn_s_barrier();                 \
                __builtin_amdgcn_sched_barrier(0);

#define RD_A(HM)                                                                   \
    _Pragma("unroll")                                                              \
    for (int i = 0; i < 4; ++i) {                                                  \
        ra[i][0] = *(const bf16x8*)&lds[aB + ((HM)*64 + i*16 + lm)*64 + cc0];      \
        ra[i][1] = *(const bf16x8*)&lds[aB + ((HM)*64 + i*16 + lm)*64 + cc1];      \
    }

#define RD_B(HN, RB)                                                               \
    _Pragma("unroll")                                                              \
    for (int j = 0; j < 2; ++j) {                                                  \
        RB[j][0] = *(const bf16x8*)&lds[bB + (bh + (HN)*32 + j*16 + lm)*64 + cc0]; \
        RB[j][1] = *(const bf16x8*)&lds[bB + (bh + (HN)*32 + j*16 + lm)*64 + cc1]; \
    }

#define MFMA_Q(HM, HN, RB)                                                         \
    _Pragma("unroll")                                                              \
    for (int i = 0; i < 4; ++i)                                                    \
        _Pragma("unroll")                                                          \
        for (int j = 0; j < 2; ++j) {                                              \
            acc[(HM)*4+i][(HN)*2+j] = __builtin_amdgcn_mfma_f32_16x16x32_bf16(     \
                ra[i][0], RB[j][0], acc[(HM)*4+i][(HN)*2+j], 0, 0, 0);             \
            acc[(HM)*4+i][(HN)*2+j] = __builtin_amdgcn_mfma_f32_16x16x32_bf16(     \
                ra[i][1], RB[j][1], acc[(HM)*4+i][(HN)*2+j], 0, 0, 0);             \
        }

// tile t (buffer BUF): phases read quadrants (0,0),(0,1),(1,0),(1,1);
// stages: ph0 -> A1(t+1) [other buf], ph2 -> B0(t+2), ph3 -> B1(t+2)+A0(t+2) [this buf]
#define KTILE(TT, BUF)                                                             \
    {                                                                              \
        const int kt1 = ((TT)+1 < nt ? (TT)+1 : nt-1) * 64;                        \
        const int kt2 = ((TT)+2 < nt ? (TT)+2 : nt-1) * 64;                        \
        const int aB = ((BUF)*2 + wm) * 8192;                                      \
        const int bB = 32768 + ((BUF)*2 + (wn >> 1)) * 8192;                       \
        /* phase 0 */                                                              \
        RD_A(0) RD_B(0, rb0)                                                       \
        stage_half(Aptr, m0 + 128, kt1, K, lds + ((((BUF)^1)*2 + 1) * 8192), tid); \
        PH_MID  MFMA_Q(0, 0, rb0)  PH_END                                          \
        /* phase 1 */                                                              \
        RD_B(1, rb1)                                                               \
        PH_MID  MFMA_Q(0, 1, rb1)  PH_END                                          \
        /* phase 2 */                                                              \
        RD_A(1)                                                                    \
        stage_half(Wptr, n0, kt2, K, lds + (32768 + ((BUF)*2) * 8192), tid);       \
        PH_MID  MFMA_Q(1, 0, rb0)  PH_END                                          \
        /* phase 3 */                                                              \
        stage_half(Wptr, n0 + 128, kt2, K, lds + (32768 + ((BUF)*2+1) * 8192), tid); \
        stage_half(Aptr, m0,       kt2, K, lds + (((BUF)*2) * 8192), tid);         \
        PH_MID  MFMA_Q(1, 1, rb1)                                                  \
        __builtin_amdgcn_s_setprio(0);                                             \
        asm volatile("s_waitcnt vmcnt(6)");                                        \
        __builtin_amdgcn_s_barrier();                                              \
        __builtin_amdgcn_sched_barrier(0);                                         \
    }

__global__ __launch_bounds__(512) void gemm_8ph(const u16* __restrict__ Xraw,
                                                const u16* __restrict__ Xconv,
                                                const u16* __restrict__ Wmat,
                                                const void* __restrict__ bias,
                                                void* __restrict__ out,
                                                const int* __restrict__ flags,
                                                int M, int N, int K) {
    __shared__ __align__(16) u16 lds[65536];   // 128 KiB

    const int mode = flags[0];
    const u16* Aptr = (mode == 1) ? Xraw : Xconv;
    const u16* Wptr = Wmat;

    const int tid  = threadIdx.x;
    const int lane = tid & 63;
    const int wid  = tid >> 6;
    const int wm   = wid >> 2;        // 0..1 (M)
    const int wn   = wid & 3;         // 0..3 (N)
    const int lm   = lane & 15;
    const int kg   = lane >> 4;
    const int bh   = (wn & 1) * 64;
    const int swzu = (lm & 7) * 8;                 // 8*(row&7): all frag rows ≡ lm (mod 8)
    const int cc0  = (kg * 8) ^ swzu;
    const int cc1  = (32 + kg * 8) ^ swzu;

    const int gn = N / 256;
    const int b  = blockIdx.x;
    const int per = gridDim.x >> 3;
    const int sw = ((per << 3) == (int)gridDim.x) ? ((b & 7) * per + (b >> 3)) : b;
    const int m0 = (sw / gn) * 256;
    const int n0 = (sw % gn) * 256;

    const int nt = K >> 6;

    bf16x8 ra[4][2];
    bf16x8 rb0[2][2], rb1[2][2];
    f32x4 acc[8][4] = {};

    // prologue: tile0 fully (A0,A1,B0,B1) + tile1 (A0,B0,B1); tile1.A1 staged at ph0 of tile0
    stage_half(Aptr, m0,       0,  K, lds + 0,             tid);
    stage_half(Aptr, m0 + 128, 0,  K, lds + 8192,          tid);
    stage_half(Wptr, n0,       0,  K, lds + 32768,         tid);
    stage_half(Wptr, n0 + 128, 0,  K, lds + 32768 + 8192,  tid);
    stage_half(Aptr, m0,       64, K, lds + 2 * 8192,      tid);
    stage_half(Wptr, n0,       64, K, lds + 32768 + 2 * 8192, tid);
    stage_half(Wptr, n0 + 128, 64, K, lds + 32768 + 3 * 8192, tid);
    asm volatile("s_waitcnt vmcnt(6)");
    __builtin_amdgcn_s_barrier();
    __builtin_amdgcn_sched_barrier(0);

    for (int t = 0; t < nt; t += 2) {
        KTILE(t, 0)
        KTILE(t + 1, 1)
    }

    // epilogue
    const int rr4 = (lane >> 4) * 4;
    #pragma unroll
    for (int j = 0; j < 4; ++j) {
        const int col = n0 + wn * 64 + j * 16 + lm;
        const float bvf = load_bias(bias, col, mode);
        #pragma unroll
        for (int i = 0; i < 8; ++i) {
            const int row = m0 + wm * 128 + i * 16 + rr4;
            #pragma unroll
            for (int r = 0; r < 4; ++r)
                store_out(out, (size_t)(row + r) * N + col, acc[i][j][r] + bvf, mode);
        }
    }
}

// ---------------- fallback (tiny ws): fused 128-tile ----------------
__global__ __launch_bounds__(256) void gemm_fallback(const void* __restrict__ x,
                                                     const uint8_t* __restrict__ qraw,
                                                     const void* __restrict__ bias,
                                                     void* __restrict__ out,
                                                     const int* __restrict__ flags,
                                                     int M, int N, int K, int has_flags) {
    __shared__ __align__(16) u16 lA[128 * 64];
    __shared__ __align__(16) u16 lB[128 * 64];

    const int mode = has_flags ? flags[0] : 0;
    const int qm   = has_flags ? flags[1] : 0;

    const int tid  = threadIdx.x;
    const int lane = tid & 63;
    const int wid  = tid >> 6;
    const int gn   = N / 128;

    const int b   = blockIdx.x;
    const int per = gridDim.x >> 3;
    const int sw  = ((per << 3) == (int)gridDim.x) ? ((b & 7) * per + (b >> 3)) : b;
    const int m0  = (sw / gn) * 128;
    const int n0  = (sw % gn) * 128;

    const int wm = wid >> 1, wn = wid & 1;
    const int lm = lane & 15;
    const int kg = lane >> 4;
    const int rowQ = tid >> 1, halfQ = tid & 1;

    f32x4 acc[4][4] = {};

    for (int k0 = 0; k0 < K; k0 += 64) {
        #pragma unroll
        for (int rep = 0; rep < 4; ++rep) {
            const int c = rep * 256 + tid;
            const int row = c >> 3, col = (c & 7) * 8;
            union { u16 h[8]; uint4 v; } o;
            if (mode == 0) {
                const float4* xf = (const float4*)x + ((size_t)(m0 + row) * K + k0 + col) / 4;
                float4 a = xf[0], b2 = xf[1];
                o.h[0] = f2bf(a.x);  o.h[1] = f2bf(a.y);  o.h[2] = f2bf(a.z);  o.h[3] = f2bf(a.w);
                o.h[4] = f2bf(b2.x); o.h[5] = f2bf(b2.y); o.h[6] = f2bf(b2.z); o.h[7] = f2bf(b2.w);
            } else {
                uint4 v = *(const uint4*)((const u16*)x + (size_t)(m0 + row) * K + k0 + col);
                if (mode == 1) o.v = v;
                else {
                    const u16* hh = (const u16*)&v;
                    #pragma unroll
                    for (int i = 0; i < 8; ++i) o.h[i] = f2bf(h2f(hh[i]));
                }
            }
            *(uint4*)&lA[row * 64 + col] = o.v;
        }
        {
            const size_t blk = (size_t)(n0 + rowQ) * (K >> 5) + (k0 >> 5) + halfQ;
            uint32_t bb[18];
            fetch18(qraw, qm, blk, bb);
            union { u16 h[32]; uint4 v[4]; } o;
            decode32(bb, o.h);
            uint4* dst = (uint4*)&lB[rowQ * 64 + halfQ * 32];
            dst[0] = o.v[0]; dst[1] = o.v[1]; dst[2] = o.v[2]; dst[3] = o.v[3];
        }
        __syncthreads();

        #pragma unroll
        for (int kk = 0; kk < 2; ++kk) {
            bf16x8 av[4], bv[4];
            #pragma unroll
            for (int i = 0; i < 4; ++i) {
                av[i] = *(const bf16x8*)&lA[(wm * 64 + i * 16 + lm) * 64 + kk * 32 + kg * 8];
                bv[i] = *(const bf16x8*)&lB[(wn * 64 + i * 16 + lm) * 64 + kk * 32 + kg * 8];
            }
            #pragma unroll
            for (int i = 0; i < 4; ++i)
                #pragma unroll
                for (int j = 0; j < 4; ++j)
                    acc[i][j] = __builtin_amdgcn_mfma_f32_16x16x32_bf16(av[i], bv[j], acc[i][j], 0, 0, 0);
        }
        __syncthreads();
    }

    const int rg = (lane >> 4) * 4;
    #pragma unroll
    for (int j = 0; j < 4; ++j) {
        const int col = n0 + wn * 64 + j * 16 + lm;
        const float bvf = load_bias(bias, col, mode);
        #pragma unroll
        for (int i = 0; i < 4; ++i) {
            const int row = m0 + wm * 64 + i * 16 + rg;
            #pragma unroll
            for (int r = 0; r < 4; ++r)
                store_out(out, (size_t)(row + r) * N + col, acc[i][j][r] + bvf, mode);
        }
    }
}

extern "C" void kernel_launch(void* const* d_in, const int* in_sizes, int n_in,
                              void* d_out, int out_size, void* d_ws, size_t ws_size,
                              hipStream_t stream) {
    const void*    x    = d_in[0];
    const uint8_t* qw   = (const uint8_t*)d_in[1];
    const void*    bias = d_in[2];

    const int N = in_sizes[2];
    const int row_elems = in_sizes[1] / N;
    const int K = (row_elems / 18) * 32;
    const int M = in_sizes[0] / K;

    const size_t offW = 256;
    const size_t offX = offW + (size_t)N * K * 2;
    const size_t need = offX + (size_t)M * K * 2;

    const int nt = K >> 6;
    const bool big_ok = (M % 256 == 0) && (N % 256 == 0) && (nt >= 4) && ((nt & 1) == 0);

    if (ws_size >= need && big_ok) {
        int* flags = (int*)d_ws;
        u16* W = (u16*)((char*)d_ws + offW);
        u16* X = (u16*)((char*)d_ws + offX);
        detect_kernel<<<1, 64, 0, stream>>>((const uint32_t*)x, (const uint32_t*)qw, flags);
        const int nblocks = N * (K >> 5);
        dequant_kernel<<<(nblocks + 255) / 256, 256, 0, stream>>>(qw, W, nblocks, flags);
        const size_t n8 = (size_t)M * K / 8;
        convertx_kernel<<<(int)((n8 + 255) / 256), 256, 0, stream>>>(x, X, n8, flags);
        gemm_8ph<<<(M / 256) * (N / 256), 512, 0, stream>>>((const u16*)x, X, W, bias,
                                                            d_out, flags, M, N, K);
    } else if (ws_size >= 16) {
        int* flags = (int*)d_ws;
        detect_kernel<<<1, 64, 0, stream>>>((const uint32_t*)x, (const uint32_t*)qw, flags);
        gemm_fallback<<<(M / 128) * (N / 128), 256, 0, stream>>>(x, qw, bias, d_out, flags, M, N, K, 1);
    } else {
        gemm_fallback<<<(M / 128) * (N / 128), 256, 0, stream>>>(x, qw, bias, d_out, nullptr, M, N, K, 0);
    }
}

// Round 5
// 297.476 us; speedup vs baseline: 1.5410x; 1.0145x over previous
//
#include <hip/hip_runtime.h>
#include <stdint.h>

typedef unsigned short u16;
typedef __attribute__((ext_vector_type(8))) __bf16 bf16x8;
typedef __attribute__((ext_vector_type(4))) float f32x4;

// ---------------- scalar helpers ----------------
__device__ __forceinline__ u16 f2bf(float f) {
    uint32_t u = __float_as_uint(f);
    u += 0x7FFF + ((u >> 16) & 1);   // RNE
    return (u16)(u >> 16);
}
__device__ __forceinline__ float bf2f(u16 b) {
    return __uint_as_float(((uint32_t)b) << 16);
}
__device__ __forceinline__ float h2f(u16 h) {
    float r; uint32_t x = h;
    asm volatile("v_cvt_f32_f16_e32 %0, %1" : "=v"(r) : "v"(x));
    return r;
}
__device__ __forceinline__ u16 f2h(float f) {
    uint32_t r;
    asm volatile("v_cvt_f16_f32_e32 %0, %1" : "=v"(r) : "v"(f));
    return (u16)r;
}

// ---------------- dtype detection ----------------
// flags[0]: x/bias/out mode: 0=float32, 1=bf16(u16), 2=fp16(u16)
// flags[1]: qweight mode:    0=packed bytes, 1=one byte per int32
__global__ void detect_kernel(const uint32_t* __restrict__ xw,
                              const uint32_t* __restrict__ qw,
                              int* __restrict__ flags) {
    if (blockIdx.x | threadIdx.x) return;
    bool allz = true;
    for (int i = 0; i < 64; ++i) allz = allz && ((xw[i] & 0x1FFFu) == 0u);
    int mode;
    if (allz) mode = 0;
    else {
        const u16* xh = (const u16*)xw;
        int tiny = 0;
        for (int i = 0; i < 256; ++i) {
            u16 mag = xh[i] & 0x7FFF;
            if (mag != 0 && (mag >> 7) < 118) ++tiny;
        }
        mode = (tiny >= 16) ? 2 : 1;
    }
    bool bytes = false;
    for (int i = 0; i < 64; ++i) bytes = bytes || (qw[i] > 255u);
    flags[0] = mode;
    flags[1] = bytes ? 0 : 1;
}

// ---------------- q4_0 decode ----------------
__device__ __forceinline__ void fetch18(const uint8_t* __restrict__ qraw, int qm,
                                        size_t blk, uint32_t b[18]) {
    if (qm == 0) {
        const uint8_t* p = qraw + blk * 18;
        #pragma unroll
        for (int i = 0; i < 18; ++i) b[i] = p[i];
    } else {
        const int* p = (const int*)qraw + blk * 18;
        #pragma unroll
        for (int i = 0; i < 18; ++i) b[i] = ((uint32_t)p[i]) & 0xFFu;
    }
}
__device__ __forceinline__ void decode32(const uint32_t b[18], u16 o[32]) {
    const float d = h2f((u16)(b[0] | (b[1] << 8)));
    #pragma unroll
    for (int i = 0; i < 16; ++i) {
        o[i]      = f2bf(d * (float)((int)(b[2 + i] & 15u) - 8));
        o[16 + i] = f2bf(d * (float)((int)(b[2 + i] >> 4) - 8));
    }
}

__global__ __launch_bounds__(256) void dequant_kernel(const uint8_t* __restrict__ qraw,
                                                      u16* __restrict__ W, int nblocks,
                                                      const int* __restrict__ flags) {
    const int qm = flags[1];
    const int t = blockIdx.x * 256 + threadIdx.x;
    if (t >= nblocks) return;
    uint32_t b[18];
    fetch18(qraw, qm, (size_t)t, b);
    union { u16 h[32]; uint4 v[4]; } o;
    decode32(b, o.h);
    uint4* dst = (uint4*)(W + (size_t)t * 32);
    dst[0] = o.v[0]; dst[1] = o.v[1]; dst[2] = o.v[2]; dst[3] = o.v[3];
}

// ---------------- x -> bf16 ----------------
__global__ __launch_bounds__(256) void convertx_kernel(const void* __restrict__ x,
                                                       u16* __restrict__ X, size_t n8,
                                                       const int* __restrict__ flags) {
    const int mode = flags[0];
    if (mode == 1) return;
    const size_t t = (size_t)blockIdx.x * 256 + threadIdx.x;
    if (t >= n8) return;
    union { u16 h[8]; uint4 v; } o;
    if (mode == 0) {
        const float4* xf = (const float4*)x;
        float4 a = xf[2 * t], b = xf[2 * t + 1];
        o.h[0] = f2bf(a.x); o.h[1] = f2bf(a.y); o.h[2] = f2bf(a.z); o.h[3] = f2bf(a.w);
        o.h[4] = f2bf(b.x); o.h[5] = f2bf(b.y); o.h[6] = f2bf(b.z); o.h[7] = f2bf(b.w);
    } else {
        uint4 v = ((const uint4*)x)[t];
        const u16* hh = (const u16*)&v;
        #pragma unroll
        for (int i = 0; i < 8; ++i) o.h[i] = f2bf(h2f(hh[i]));
    }
    ((uint4*)X)[t] = o.v;
}

// ---------------- epilogue helpers ----------------
__device__ __forceinline__ float load_bias(const void* bias, int col, int mode) {
    if (mode == 0) return ((const float*)bias)[col];
    u16 b = ((const u16*)bias)[col];
    return (mode == 1) ? bf2f(b) : h2f(b);
}
__device__ __forceinline__ void store_out(void* out, size_t idx, float v, int mode) {
    if (mode == 0)      ((float*)out)[idx] = v;
    else if (mode == 1) ((u16*)out)[idx] = f2bf(v);
    else                ((u16*)out)[idx] = f2h(v);
}

// ---------------- 256x256 8-subphase pipelined GEMM ----------------
// LDS (u16): A(buf,half) at (buf*2+half)*8192 ; B at 32768 + (buf*2+half)*8192.
// Swizzle: LDS[row][col ^ 8*(row&7)], both staged (global src pre-swizzled) and read.
// Each K-tile = 8 sub-phases x 8 MFMA; every ds_read issued ONE sub-phase before
// its consuming MFMA with counted lgkmcnt -> LDS transfer overlaps MFMA.
__device__ __forceinline__ void stage_half(const u16* __restrict__ G, int row0, int k0,
                                           int kstride, u16* dstreg, int tid) {
    const int l = tid & 63, w = tid >> 6;
    const int r = w * 8 + (l >> 3);
    const int c = ((l & 7) * 8) ^ (((l >> 3) & 7) * 8);   // col ^ 8*(row&7)
    #pragma unroll
    for (int ch = 0; ch < 2; ++ch) {
        const u16* src = G + (size_t)(row0 + ch * 64 + r) * kstride + (k0 + c);
        u16* dst = dstreg + ch * 4096 + w * 512;     // wave-uniform; HW adds lane*16B
        __builtin_amdgcn_global_load_lds(
            (const __attribute__((address_space(1))) uint32_t*)src,
            (__attribute__((address_space(3))) uint32_t*)dst, 16, 0, 0);
    }
}

#define SEG_MID(N)  __builtin_amdgcn_s_barrier();                      \
                    asm volatile("s_waitcnt lgkmcnt(" #N ")");         \
                    __builtin_amdgcn_sched_barrier(0);                 \
                    __builtin_amdgcn_s_setprio(1);

#define SEG_CUT     __builtin_amdgcn_s_setprio(0);                     \
                    __builtin_amdgcn_sched_barrier(0);

#define SEG_ENDBAR  __builtin_amdgcn_s_setprio(0);                     \
                    __builtin_amdgcn_s_barrier();                      \
                    __builtin_amdgcn_sched_barrier(0);

#define RD_A(DST, BASE, HM, KK)                                                         \
    _Pragma("unroll")                                                                   \
    for (int i = 0; i < 4; ++i)                                                         \
        DST[i] = *(const bf16x8*)&lds[(BASE) + ((HM)*64 + i*16 + lm)*64 + ((KK) ? cc1 : cc0)];

#define RD_B(DST, BASE, HN, KK)                                                         \
    _Pragma("unroll")                                                                   \
    for (int j = 0; j < 2; ++j)                                                         \
        DST[j] = *(const bf16x8*)&lds[(BASE) + (bh + (HN)*32 + j*16 + lm)*64 + ((KK) ? cc1 : cc0)];

#define MFMA8(ASET, BSET, R, C)                                                         \
    _Pragma("unroll")                                                                   \
    for (int i = 0; i < 4; ++i)                                                         \
        _Pragma("unroll")                                                               \
        for (int j = 0; j < 2; ++j)                                                     \
            acc[(R)+i][(C)+j] = __builtin_amdgcn_mfma_f32_16x16x32_bf16(                \
                ASET[i], BSET[j], acc[(R)+i][(C)+j], 0, 0, 0);

// Sub-phase s uses (HM,HN,kk); reads for s+1 issued pre-barrier in s.
// Frag reg sets: a0/a1 alternate A-half-K sets; b00..b11 resident per K-tile.
// Stages: s2 -> B halves (t+2, this buf), s6 -> A halves. vmcnt(4)+barrier at s4
// retires tile t+1's buffers before cross-tile reads (s5..s7, s0').
#define KTILE(TT, BUF)                                                                  \
    {                                                                                   \
        const int kt2 = ((TT)+2 < nt ? (TT)+2 : nt-1) * 64;                             \
        const int aB  = ((BUF)*2 + wm) * 8192;                                          \
        const int bB  = 32768 + ((BUF)*2 + (wn >> 1)) * 8192;                           \
        const int aBo = (((BUF)^1)*2 + wm) * 8192;                                      \
        const int bBo = 32768 + (((BUF)^1)*2 + (wn >> 1)) * 8192;                       \
        /* s0: (0,0,k0) */                                                              \
        RD_A(a1, aB, 0, 1) RD_B(b11, bB, 1, 1)                                          \
        SEG_MID(6)  MFMA8(a0, b00, 0, 0)  SEG_CUT                                       \
        /* s1: (0,0,k1) */                                                              \
        SEG_MID(0)  MFMA8(a1, b01, 0, 0)  SEG_ENDBAR                                    \
        /* s2: (0,1,k0) + stage B(t+2) */                                               \
        stage_half(Wptr, n0,       kt2, K, lds + (32768 + ((BUF)*2)*8192), tid);        \
        stage_half(Wptr, n0 + 128, kt2, K, lds + (32768 + ((BUF)*2+1)*8192), tid);      \
        SEG_MID(0)  MFMA8(a0, b10, 0, 2)  SEG_CUT                                       \
        /* s3: (0,1,k1) */                                                              \
        RD_A(a0, aB, 1, 0)                                                              \
        SEG_MID(4)  MFMA8(a1, b11, 0, 2)  SEG_CUT                                       \
        /* s4: (1,0,k0) + vmcnt for t+1 readiness */                                    \
        RD_A(a1, aB, 1, 1)                                                              \
        SEG_MID(4)  MFMA8(a0, b00, 4, 0)                                                \
        __builtin_amdgcn_s_setprio(0);                                                  \
        asm volatile("s_waitcnt vmcnt(4)" ::: "memory");                                \
        __builtin_amdgcn_s_barrier();                                                   \
        __builtin_amdgcn_sched_barrier(0);                                              \
        /* s5: (1,0,k1) */                                                              \
        RD_B(b00, bBo, 0, 0)                                                            \
        SEG_MID(2)  MFMA8(a1, b01, 4, 0)  SEG_ENDBAR                                    \
        /* s6: (1,1,k0) + stage A(t+2) */                                               \
        stage_half(Aptr, m0,       kt2, K, lds + (((BUF)*2)*8192), tid);                \
        stage_half(Aptr, m0 + 128, kt2, K, lds + (((BUF)*2+1)*8192), tid);              \
        RD_B(b01, bBo, 0, 1)                                                            \
        SEG_MID(2)  MFMA8(a0, b10, 4, 2)  SEG_CUT                                       \
        /* s7: (1,1,k1) */                                                              \
        RD_B(b10, bBo, 1, 0) RD_A(a0, aBo, 0, 0)                                        \
        SEG_MID(6)  MFMA8(a1, b11, 4, 2)  SEG_CUT                                       \
    }

__global__ __launch_bounds__(512) void gemm_8ph(const u16* __restrict__ Xraw,
                                                const u16* __restrict__ Xconv,
                                                const u16* __restrict__ Wmat,
                                                const void* __restrict__ bias,
                                                void* __restrict__ out,
                                                const int* __restrict__ flags,
                                                int M, int N, int K) {
    __shared__ __align__(16) u16 lds[65536];   // 128 KiB

    const int mode = flags[0];
    const u16* Aptr = (mode == 1) ? Xraw : Xconv;
    const u16* Wptr = Wmat;

    const int tid  = threadIdx.x;
    const int lane = tid & 63;
    const int wid  = tid >> 6;
    const int wm   = wid >> 2;        // 0..1 (M)
    const int wn   = wid & 3;         // 0..3 (N)
    const int lm   = lane & 15;
    const int kg   = lane >> 4;
    const int bh   = (wn & 1) * 64;
    const int swzu = (lm & 7) * 8;                 // 8*(row&7)
    const int cc0  = (kg * 8) ^ swzu;
    const int cc1  = (32 + kg * 8) ^ swzu;

    const int gn = N / 256;
    const int b  = blockIdx.x;
    const int per = gridDim.x >> 3;
    const int sw = ((per << 3) == (int)gridDim.x) ? ((b & 7) * per + (b >> 3)) : b;
    const int m0 = (sw / gn) * 256;
    const int n0 = (sw % gn) * 256;

    const int nt = K >> 6;

    bf16x8 a0[4], a1[4];
    bf16x8 b00[2], b01[2], b10[2], b11[2];
    f32x4 acc[8][4] = {};

    // prologue: stage tiles 0 and 1 fully
    stage_half(Aptr, m0,       0,  K, lds + 0,                tid);
    stage_half(Aptr, m0 + 128, 0,  K, lds + 8192,             tid);
    stage_half(Wptr, n0,       0,  K, lds + 32768,            tid);
    stage_half(Wptr, n0 + 128, 0,  K, lds + 32768 + 8192,     tid);
    stage_half(Aptr, m0,       64, K, lds + 2 * 8192,         tid);
    stage_half(Aptr, m0 + 128, 64, K, lds + 3 * 8192,         tid);
    stage_half(Wptr, n0,       64, K, lds + 32768 + 2 * 8192, tid);
    stage_half(Wptr, n0 + 128, 64, K, lds + 32768 + 3 * 8192, tid);
    asm volatile("s_waitcnt vmcnt(8)" ::: "memory");
    __builtin_amdgcn_s_barrier();
    __builtin_amdgcn_sched_barrier(0);
    // pre-reads for tile0 s0: b00,b01,b10,a0 from buf0
    {
        const int aB = wm * 8192;
        const int bB = 32768 + (wn >> 1) * 8192;
        RD_B(b00, bB, 0, 0)
        RD_B(b01, bB, 0, 1)
        RD_B(b10, bB, 1, 0)
        RD_A(a0,  aB, 0, 0)
    }
    __builtin_amdgcn_sched_barrier(0);

    for (int t = 0; t < nt; t += 2) {
        KTILE(t, 0)
        KTILE(t + 1, 1)
    }

    // epilogue: C/D layout col=lane&15, row=(lane>>4)*4+reg
    const int rr4 = (lane >> 4) * 4;
    #pragma unroll
    for (int j = 0; j < 4; ++j) {
        const int col = n0 + wn * 64 + j * 16 + lm;
        const float bvf = load_bias(bias, col, mode);
        #pragma unroll
        for (int i = 0; i < 8; ++i) {
            const int row = m0 + wm * 128 + i * 16 + rr4;
            #pragma unroll
            for (int r = 0; r < 4; ++r)
                store_out(out, (size_t)(row + r) * N + col, acc[i][j][r] + bvf, mode);
        }
    }
}

// ---------------- fallback (tiny ws): fused 128-tile ----------------
__global__ __launch_bounds__(256) void gemm_fallback(const void* __restrict__ x,
                                                     const uint8_t* __restrict__ qraw,
                                                     const void* __restrict__ bias,
                                                     void* __restrict__ out,
                                                     const int* __restrict__ flags,
                                                     int M, int N, int K, int has_flags) {
    __shared__ __align__(16) u16 lA[128 * 64];
    __shared__ __align__(16) u16 lB[128 * 64];

    const int mode = has_flags ? flags[0] : 0;
    const int qm   = has_flags ? flags[1] : 0;

    const int tid  = threadIdx.x;
    const int lane = tid & 63;
    const int wid  = tid >> 6;
    const int gn   = N / 128;

    const int b   = blockIdx.x;
    const int per = gridDim.x >> 3;
    const int sw  = ((per << 3) == (int)gridDim.x) ? ((b & 7) * per + (b >> 3)) : b;
    const int m0  = (sw / gn) * 128;
    const int n0  = (sw % gn) * 128;

    const int wm = wid >> 1, wn = wid & 1;
    const int lm = lane & 15;
    const int kg = lane >> 4;
    const int rowQ = tid >> 1, halfQ = tid & 1;

    f32x4 acc[4][4] = {};

    for (int k0 = 0; k0 < K; k0 += 64) {
        #pragma unroll
        for (int rep = 0; rep < 4; ++rep) {
            const int c = rep * 256 + tid;
            const int row = c >> 3, col = (c & 7) * 8;
            union { u16 h[8]; uint4 v; } o;
            if (mode == 0) {
                const float4* xf = (const float4*)x + ((size_t)(m0 + row) * K + k0 + col) / 4;
                float4 a = xf[0], b2 = xf[1];
                o.h[0] = f2bf(a.x);  o.h[1] = f2bf(a.y);  o.h[2] = f2bf(a.z);  o.h[3] = f2bf(a.w);
                o.h[4] = f2bf(b2.x); o.h[5] = f2bf(b2.y); o.h[6] = f2bf(b2.z); o.h[7] = f2bf(b2.w);
            } else {
                uint4 v = *(const uint4*)((const u16*)x + (size_t)(m0 + row) * K + k0 + col);
                if (mode == 1) o.v = v;
                else {
                    const u16* hh = (const u16*)&v;
                    #pragma unroll
                    for (int i = 0; i < 8; ++i) o.h[i] = f2bf(h2f(hh[i]));
                }
            }
            *(uint4*)&lA[row * 64 + col] = o.v;
        }
        {
            const size_t blk = (size_t)(n0 + rowQ) * (K >> 5) + (k0 >> 5) + halfQ;
            uint32_t bb[18];
            fetch18(qraw, qm, blk, bb);
            union { u16 h[32]; uint4 v[4]; } o;
            decode32(bb, o.h);
            uint4* dst = (uint4*)&lB[rowQ * 64 + halfQ * 32];
            dst[0] = o.v[0]; dst[1] = o.v[1]; dst[2] = o.v[2]; dst[3] = o.v[3];
        }
        __syncthreads();

        #pragma unroll
        for (int kk = 0; kk < 2; ++kk) {
            bf16x8 av[4], bv[4];
            #pragma unroll
            for (int i = 0; i < 4; ++i) {
                av[i] = *(const bf16x8*)&lA[(wm * 64 + i * 16 + lm) * 64 + kk * 32 + kg * 8];
                bv[i] = *(const bf16x8*)&lB[(wn * 64 + i * 16 + lm) * 64 + kk * 32 + kg * 8];
            }
            #pragma unroll
            for (int i = 0; i < 4; ++i)
                #pragma unroll
                for (int j = 0; j < 4; ++j)
                    acc[i][j] = __builtin_amdgcn_mfma_f32_16x16x32_bf16(av[i], bv[j], acc[i][j], 0, 0, 0);
        }
        __syncthreads();
    }

    const int rg = (lane >> 4) * 4;
    #pragma unroll
    for (int j = 0; j < 4; ++j) {
        const int col = n0 + wn * 64 + j * 16 + lm;
        const float bvf = load_bias(bias, col, mode);
        #pragma unroll
        for (int i = 0; i < 4; ++i) {
            const int row = m0 + wm * 64 + i * 16 + rg;
            #pragma unroll
            for (int r = 0; r < 4; ++r)
                store_out(out, (size_t)(row + r) * N + col, acc[i][j][r] + bvf, mode);
        }
    }
}

extern "C" void kernel_launch(void* const* d_in, const int* in_sizes, int n_in,
                              void* d_out, int out_size, void* d_ws, size_t ws_size,
                              hipStream_t stream) {
    const void*    x    = d_in[0];
    const uint8_t* qw   = (const uint8_t*)d_in[1];
    const void*    bias = d_in[2];

    const int N = in_sizes[2];
    const int row_elems = in_sizes[1] / N;
    const int K = (row_elems / 18) * 32;
    const int M = in_sizes[0] / K;

    const size_t offW = 256;
    const size_t offX = offW + (size_t)N * K * 2;
    const size_t need = offX + (size_t)M * K * 2;

    const int nt = K >> 6;
    const bool big_ok = (M % 256 == 0) && (N % 256 == 0) && (nt >= 4) && ((nt & 1) == 0);

    if (ws_size >= need && big_ok) {
        int* flags = (int*)d_ws;
        u16* W = (u16*)((char*)d_ws + offW);
        u16* X = (u16*)((char*)d_ws + offX);
        detect_kernel<<<1, 64, 0, stream>>>((const uint32_t*)x, (const uint32_t*)qw, flags);
        const int nblocks = N * (K >> 5);
        dequant_kernel<<<(nblocks + 255) / 256, 256, 0, stream>>>(qw, W, nblocks, flags);
        const size_t n8 = (size_t)M * K / 8;
        convertx_kernel<<<(int)((n8 + 255) / 256), 256, 0, stream>>>(x, X, n8, flags);
        gemm_8ph<<<(M / 256) * (N / 256), 512, 0, stream>>>((const u16*)x, X, W, bias,
                                                            d_out, flags, M, N, K);
    } else if (ws_size >= 16) {
        int* flags = (int*)d_ws;
        detect_kernel<<<1, 64, 0, stream>>>((const uint32_t*)x, (const uint32_t*)qw, flags);
        gemm_fallback<<<(M / 128) * (N / 128), 256, 0, stream>>>(x, qw, bias, d_out, flags, M, N, K, 1);
    } else {
        gemm_fallback<<<(M / 128) * (N / 128), 256, 0, stream>>>(x, qw, bias, d_out, nullptr, M, N, K, 0);
    }
}